// Round 1
// baseline (372.840 us; speedup 1.0000x reference)
//
#include <hip/hip_runtime.h>
#include <hip/hip_bf16.h>
#include <stdint.h>

#define NV 300000
#define KOFF 27
#define BM 128

typedef __bf16 bf16x8 __attribute__((ext_vector_type(8)));
typedef float f32x4 __attribute__((ext_vector_type(4)));
typedef unsigned short u16;

__device__ __forceinline__ u16 f2bf(float f) {
  uint32_t u = __float_as_uint(f);
  uint32_t r = (u + 0x7fffu + ((u >> 16) & 1u)) >> 16;
  return (u16)r;
}

__device__ __forceinline__ void async16(const void* g, void* l) {
  __builtin_amdgcn_global_load_lds(
      (const __attribute__((address_space(1))) uint32_t*)g,
      (__attribute__((address_space(3))) uint32_t*)l, 16, 0, 0);
}

// ---- convert x (f32) -> bf16 table ----
__global__ void cvt_x_kernel(const float* __restrict__ x, u16* __restrict__ xb,
                             int n) {
  int i = (blockIdx.x * 256 + threadIdx.x) * 8;
  if (i >= n) return;
  const float4 a = *(const float4*)(x + i);
  const float4 b = *(const float4*)(x + i + 4);
  uint4 o;
  o.x = (uint32_t)f2bf(a.x) | ((uint32_t)f2bf(a.y) << 16);
  o.y = (uint32_t)f2bf(a.z) | ((uint32_t)f2bf(a.w) << 16);
  o.z = (uint32_t)f2bf(b.x) | ((uint32_t)f2bf(b.y) << 16);
  o.w = (uint32_t)f2bf(b.z) | ((uint32_t)f2bf(b.w) << 16);
  *(uint4*)(xb + i) = o;
}

// ---- convert W -> bf16, transposed to [k][co][ci], XOR-pre-swizzled ----
// physical chunk p (16B = 8 elems) of row `col` holds logical chunk p^(col&7)
__global__ void cvt_w_kernel(const float* __restrict__ W0,
                             const float* __restrict__ W1,
                             u16* __restrict__ W0t, u16* __restrict__ W1t) {
  int t = blockIdx.x * 256 + threadIdx.x;  // 27648 total
  const float* W = W0;
  u16* Wt = W0t;
  if (t >= 13824) { W = W1; Wt = W1t; t -= 13824; }
  const int p = t & 7;
  const int col = (t >> 3) & 63;   // output channel
  const int k = t >> 9;            // 0..26
  const int c = p ^ (col & 7);     // logical chunk (ci block)
  u16 h[8];
#pragma unroll
  for (int j = 0; j < 8; j++)
    h[j] = f2bf(W[((size_t)k * 64 + c * 8 + j) * 64 + col]);
  uint4 o;
  o.x = (uint32_t)h[0] | ((uint32_t)h[1] << 16);
  o.y = (uint32_t)h[2] | ((uint32_t)h[3] << 16);
  o.z = (uint32_t)h[4] | ((uint32_t)h[5] << 16);
  o.w = (uint32_t)h[6] | ((uint32_t)h[7] << 16);
  *(uint4*)(Wt + ((size_t)k * 64 + col) * 64 + p * 8) = o;
}

// ---- gather-GEMM conv: out[r,:] = sum_k tab[nbr[k,r],:] @ W[k] (+bias,+...)
// MODE 0: relu, bf16 out (mid table).  MODE 1: +residual(f32 x), f32 out.
template <int MODE>
__global__ __launch_bounds__(256) void conv_kernel(
    const u16* __restrict__ tab,   // [NV][64] bf16
    const u16* __restrict__ Wt,    // [27][64][64] bf16 (swizzled B^T)
    const float* __restrict__ bias,
    const int* __restrict__ nbr,   // [27][NV]
    const float* __restrict__ resid, void* __restrict__ outp) {
  __shared__ __align__(16) u16 lsA[2][BM * 64];   // 2 x 16KB
  __shared__ __align__(16) u16 lsW[2][64 * 64];   // 2 x 8KB
  const int t = threadIdx.x;
  const int w = t >> 6;
  const int l = t & 63;
  const int row0 = blockIdx.x * BM;

  f32x4 acc[2][4] = {};

  float bv[4];
#pragma unroll
  for (int n = 0; n < 4; n++) bv[n] = bias[n * 16 + (l & 15)];

  int idxr[4];

  auto loadIdx = [&](int k) {
#pragma unroll
    for (int q = 0; q < 4; q++) {
      const int slot = w * 4 + q;
      const int r = slot * 8 + (l >> 3);
      const int gr = row0 + r;
      idxr[q] = (gr < NV) ? nbr[(size_t)k * NV + gr] : 0;
    }
  };

  auto issueStage = [&](int bi, int k) {
#pragma unroll
    for (int q = 0; q < 4; q++) {
      const int slot = w * 4 + q;               // 1KB LDS slot, wave-uniform
      const int r = slot * 8 + (l >> 3);        // tile row this lane feeds
      const int seg = (l & 7) ^ (r & 7);        // pre-swizzled source chunk
      async16(tab + (size_t)idxr[q] * 64 + seg * 8,
              (char*)(&lsA[bi][0]) + slot * 1024);
    }
    const char* wsrc = (const char*)(Wt + (size_t)k * 4096);
#pragma unroll
    for (int q = 0; q < 2; q++) {
      const int slot = w * 2 + q;
      async16(wsrc + slot * 1024 + (size_t)l * 16,
              (char*)(&lsW[bi][0]) + slot * 1024);
    }
  };

  auto compute = [&](int bi) {
    const char* A = (const char*)(&lsA[bi][0]);
    const char* B = (const char*)(&lsW[bi][0]);
    bf16x8 af[2][2], bf[4][2];
#pragma unroll
    for (int n = 0; n < 4; n++) {
      const int col = n * 16 + (l & 15);
#pragma unroll
      for (int kk = 0; kk < 2; kk++) {
        const int c = kk * 4 + (l >> 4);
        bf[n][kk] = *(const bf16x8*)(B + col * 128 + ((c ^ (col & 7)) * 16));
      }
    }
#pragma unroll
    for (int m = 0; m < 2; m++) {
      const int row = w * 32 + m * 16 + (l & 15);
#pragma unroll
      for (int kk = 0; kk < 2; kk++) {
        const int c = kk * 4 + (l >> 4);
        af[m][kk] = *(const bf16x8*)(A + row * 128 + ((c ^ (row & 7)) * 16));
      }
    }
#pragma unroll
    for (int m = 0; m < 2; m++)
#pragma unroll
      for (int n = 0; n < 4; n++)
#pragma unroll
        for (int kk = 0; kk < 2; kk++)
          acc[m][n] = __builtin_amdgcn_mfma_f32_16x16x32_bf16(
              af[m][kk], bf[n][kk], acc[m][n], 0, 0, 0);
  };

  loadIdx(0);
  issueStage(0, 0);
#pragma unroll 1
  for (int k = 0; k < KOFF; k++) {
    const int bi = k & 1;
    if (k + 1 < KOFF) loadIdx(k + 1);
    asm volatile("s_waitcnt vmcnt(0)" ::: "memory");
    __syncthreads();
    if (k + 1 < KOFF) issueStage(bi ^ 1, k + 1);
    compute(bi);
  }

  // epilogue: C/D layout col=lane&15, row=(lane>>4)*4+j  [m89]
#pragma unroll
  for (int m = 0; m < 2; m++) {
#pragma unroll
    for (int n = 0; n < 4; n++) {
      const int col = n * 16 + (l & 15);
#pragma unroll
      for (int j = 0; j < 4; j++) {
        const int row = row0 + w * 32 + m * 16 + (l >> 4) * 4 + j;
        if (row < NV) {
          float v = acc[m][n][j] + bv[n];
          if (MODE == 0) {
            ((u16*)outp)[(size_t)row * 64 + col] = f2bf(v < 0.f ? 0.f : v);
          } else {
            ((float*)outp)[(size_t)row * 64 + col] =
                v + resid[(size_t)row * 64 + col];
          }
        }
      }
    }
  }
}

extern "C" void kernel_launch(void* const* d_in, const int* in_sizes, int n_in,
                              void* d_out, int out_size, void* d_ws,
                              size_t ws_size, hipStream_t stream) {
  const float* x = (const float*)d_in[0];
  const float* W0 = (const float*)d_in[1];
  const float* b0 = (const float*)d_in[2];
  const float* W1 = (const float*)d_in[3];
  const float* b1 = (const float*)d_in[4];
  const int* nbr = (const int*)d_in[5];

  // ws layout: xb 38.4MB | midb 38.4MB | W0t 216KB | W1t 216KB
  if (ws_size < 77242368) return;  // clean fail -> distinguishes ws issue
  char* ws = (char*)d_ws;
  u16* xb = (u16*)(ws);
  u16* midb = (u16*)(ws + 38400000);
  u16* W0t = (u16*)(ws + 76800000);
  u16* W1t = (u16*)(ws + 77021184);

  cvt_w_kernel<<<108, 256, 0, stream>>>(W0, W1, W0t, W1t);
  cvt_x_kernel<<<9375, 256, 0, stream>>>(x, xb, NV * 64);

  const int nblk = (NV + BM - 1) / BM;  // 2344
  conv_kernel<0><<<nblk, 256, 0, stream>>>(xb, W0t, b0, nbr, nullptr, midb);
  conv_kernel<1><<<nblk, 256, 0, stream>>>(midb, W1t, b1, nbr, x, d_out);
}